// Round 7
// baseline (874.610 us; speedup 1.0000x reference)
//
#include <hip/hip_runtime.h>
#include <math.h>

#define B_    32
#define H_    128
#define C_    512
#define R_    64
#define S_    4096
#define NS_   8
#define D_    576      // C_ + R_
#define HALF_ 32
#define HT    32       // heads per block
#define KB    32       // kv positions per chunk
#define PK    584      // k_lds pitch (halfs), 1168 B rows
#define PSL   33       // s_lds pitch (f32)
#define PPL   40       // p_lds pitch (halfs), 80 B rows (16B-aligned)

typedef _Float16 half8   __attribute__((ext_vector_type(8)));
typedef _Float16 half4_t __attribute__((ext_vector_type(4)));
typedef float    f32x4   __attribute__((ext_vector_type(4)));

// ---------------- RoPE kernels (in-place; harness restores inputs pre-launch) --

__global__ __launch_bounds__(256)
void rope_q_kernel(float* __restrict__ q, const float* __restrict__ cache,
                   const int* __restrict__ positions) {
    int t = blockIdx.x * 256 + threadIdx.x;
    if (t >= B_ * H_ * HALF_) return;
    int i = t & (HALF_ - 1);
    int h = (t >> 5) & (H_ - 1);
    int b = t >> 12;
    int pos = positions[b];
    float c = cache[pos * R_ + i];
    float s = cache[pos * R_ + HALF_ + i];
    float* qp = q + (size_t)(b * H_ + h) * D_ + C_;
    float lo = qp[i], hi = qp[i + HALF_];
    qp[i]         = lo * c - hi * s;
    qp[i + HALF_] = hi * c + lo * s;
}

__global__ __launch_bounds__(256)
void rope_k_kernel(float* __restrict__ kbuf, const float* __restrict__ cache,
                   const int* __restrict__ positions, const int* __restrict__ indptr,
                   const int* __restrict__ indices, float* __restrict__ out_tail) {
    int t = blockIdx.x * 256 + threadIdx.x;
    if (t >= B_ * HALF_) return;
    int i = t & (HALF_ - 1);
    int b = t >> 5;
    int seq = indptr[b + 1] - indptr[b];
    int row = indices[b * S_ + seq - 1];
    int pos = positions[b];
    float c = cache[pos * R_ + i];
    float s = cache[pos * R_ + HALF_ + i];
    float* kp = kbuf + (size_t)row * D_ + C_;
    float lo = kp[i], hi = kp[i + HALF_];
    float nlo = lo * c - hi * s;
    float nhi = hi * c + lo * s;
    kp[i] = nlo; kp[i + HALF_] = nhi;
    out_tail[b * R_ + i]         = nlo;
    out_tail[b * R_ + HALF_ + i] = nhi;
}

__global__ void zero_tail_kernel(float* p) { if (threadIdx.x == 0) p[0] = 0.f; }

// ---------------- fused split attention, fp16 MFMA, 8 waves ------------------
// Wave roles (w = 0..7):
//   scores: hm = w>>2 (head half), hv = (w>>1)&1 (kv half), ks = w&1 (K-dim half)
//   PV:     hm = w>>2,             cq = w&3 (c-quarter, 128 channels)
// V in LDS: fp16, transposed [c][k] with 16B-slot XOR swizzle:
//   phys_half(c,k) = c*32 + ((k>>3)^(c&3))*8 + (k&7)   -> b128 reads at bank floor

__global__ __launch_bounds__(512, 4)
void mla_attn_kernel(const float* __restrict__ q, const float* __restrict__ kbuf,
                     const float* __restrict__ vbuf, const int* __restrict__ indptr,
                     const int* __restrict__ indices, float* __restrict__ out) {
    __shared__ _Float16 k_lds[KB * PK];        // 37376 B
    __shared__ _Float16 v_lds[C_ * KB];        // 32768 B (swizzled transpose)
    __shared__ float    s_lds[2 * HT * PSL];   //  8448 B (two K-dim partials)
    __shared__ _Float16 p_lds[HT * PPL];       //  2560 B
    __shared__ float    m_s[HT], l_s[HT], a_s[HT];
    // total 81536 B -> 2 blocks/CU (16 waves)

    const int blk   = blockIdx.x;
    const int xcd   = blk & 7;
    const int inner = blk >> 3;
    const int htile = inner & 3;
    const int bs    = ((inner >> 2) << 3) | xcd;  // b*NS + sp
    const int b     = bs >> 3;
    const int sp    = bs & 7;
    const int h0    = htile * HT;

    const int t    = threadIdx.x;
    const int lane = t & 63;
    const int w    = t >> 6;
    const int lr   = lane & 15;
    const int kg   = lane >> 4;
    const int hm   = w >> 2;
    const int hv   = (w >> 1) & 1;
    const int ks   = w & 1;
    const int cq   = w & 3;

    const int seq   = indptr[b + 1] - indptr[b];
    const int klps  = (seq + NS_ - 1) / NS_;
    const int start = sp * klps;
    const int end   = min(start + klps, seq);

    // ---- Q A-fragments: 16 heads x 288 (this wave's K-half), fp16 ----
    half8 qf[9];
    {
        const float* qrow = q + (size_t)(b * H_ + h0 + hm * 16 + lr) * D_ + ks * 288 + kg * 8;
        #pragma unroll
        for (int s = 0; s < 9; ++s) {
            f32x4 x0 = *(const f32x4*)(qrow + s * 32);
            f32x4 x1 = *(const f32x4*)(qrow + s * 32 + 4);
            half8 h;
            h[0] = (_Float16)x0[0]; h[1] = (_Float16)x0[1];
            h[2] = (_Float16)x0[2]; h[3] = (_Float16)x0[3];
            h[4] = (_Float16)x1[0]; h[5] = (_Float16)x1[1];
            h[6] = (_Float16)x1[2]; h[7] = (_Float16)x1[3];
            qf[s] = h;
        }
    }
    if (t < HT) { m_s[t] = -INFINITY; l_s[t] = 0.f; }

    f32x4 oacc[8];
    #pragma unroll
    for (int n = 0; n < 8; ++n) oacc[n] = (f32x4){0.f, 0.f, 0.f, 0.f};

    const float sm_scale = 1.0f / 24.0f;   // 1/sqrt(576)
    const int nchunk = (end - start + KB - 1) / KB;

    const int krow = t >> 4, kseg = t & 15;   // K staging: 16 threads/row
    const int vrow = t & 31, vseg = t >> 5;   // V staging: rows spread across waves

    for (int ch = 0; ch < nchunk; ++ch) {
        const int j0 = start + ch * KB;
        __syncthreads();   // prev PV done reading p_lds/v_lds; prev QK done with k_lds

        // ---- stage K chunk: 32 rows x 576, fp32 -> fp16 LDS row-major ----
        {
            const int r = indices[b * S_ + min(j0 + krow, end - 1)];
            const float* src = kbuf + (size_t)r * D_;
            _Float16* dst = k_lds + krow * PK;
            #pragma unroll
            for (int i = 0; i < 9; ++i) {
                const int d = kseg * 4 + i * 64;
                f32x4 x = *(const f32x4*)(src + d);
                half4_t hh;
                hh[0] = (_Float16)x[0]; hh[1] = (_Float16)x[1];
                hh[2] = (_Float16)x[2]; hh[3] = (_Float16)x[3];
                *(half4_t*)(dst + d) = hh;
            }
        }
        // ---- stage V chunk: 32 rows x 512, fp32 -> fp16 LDS swizzled [c][k] ----
        {
            const int r = indices[b * S_ + min(j0 + vrow, end - 1)];
            const float* src = vbuf + (size_t)r * C_;
            const int khi = vrow >> 3, klo = vrow & 7;
            #pragma unroll
            for (int i = 0; i < 8; ++i) {
                const int c0 = vseg * 4 + i * 64;
                f32x4 x = *(const f32x4*)(src + c0);
                #pragma unroll
                for (int cc = 0; cc < 4; ++cc) {
                    const int c = c0 + cc;
                    v_lds[c * KB + (((khi ^ cc) & 3) << 3) + klo] = (_Float16)x[cc];
                }
            }
        }
        __syncthreads();

        // ---- scores: wave (hm,hv,ks) -> 16h x 16kv partial over K=288 ----
        {
            f32x4 sacc = (f32x4){0.f, 0.f, 0.f, 0.f};
            const _Float16* kp = k_lds + (hv * 16 + lr) * PK + ks * 288 + kg * 8;
            __builtin_amdgcn_s_setprio(1);
            #pragma unroll
            for (int s = 0; s < 9; ++s) {
                half8 bf = *(const half8*)(kp + s * 32);
                sacc = __builtin_amdgcn_mfma_f32_16x16x32_f16(qf[s], bf, sacc, 0, 0, 0);
            }
            __builtin_amdgcn_s_setprio(0);
            #pragma unroll
            for (int r = 0; r < 4; ++r)
                s_lds[(ks * HT + hm * 16 + kg * 4 + r) * PSL + hv * 16 + lr] = sacc[r];
        }
        __syncthreads();

        // ---- online softmax: thread (h = t>>4, jj = t&15) handles kv {jj, jj+16} ----
        {
            const int h  = t >> 4;
            const int jj = t & 15;
            float s0 = (s_lds[h * PSL + jj]        + s_lds[(HT + h) * PSL + jj])        * sm_scale;
            float s1 = (s_lds[h * PSL + jj + 16]   + s_lds[(HT + h) * PSL + jj + 16])   * sm_scale;
            const bool v0 = (j0 + jj)      < end;
            const bool v1 = (j0 + jj + 16) < end;
            if (!v0) s0 = -INFINITY;
            if (!v1) s1 = -INFINITY;
            float mx = fmaxf(s0, s1);
            mx = fmaxf(mx, __shfl_xor(mx, 1, 16));
            mx = fmaxf(mx, __shfl_xor(mx, 2, 16));
            mx = fmaxf(mx, __shfl_xor(mx, 4, 16));
            mx = fmaxf(mx, __shfl_xor(mx, 8, 16));
            const float m_old = m_s[h];
            const float m_new = fmaxf(m_old, mx);
            float p0 = v0 ? __expf(s0 - m_new) : 0.f;
            float p1 = v1 ? __expf(s1 - m_new) : 0.f;
            float ps = p0 + p1;
            ps += __shfl_xor(ps, 1, 16);
            ps += __shfl_xor(ps, 2, 16);
            ps += __shfl_xor(ps, 4, 16);
            ps += __shfl_xor(ps, 8, 16);
            p_lds[h * PPL + jj]      = (_Float16)p0;
            p_lds[h * PPL + jj + 16] = (_Float16)p1;
            if (jj == 0) {
                const float al = __expf(m_old - m_new);   // m_old=-inf -> 0
                a_s[h] = al;
                l_s[h] = l_s[h] * al + ps;
                m_s[h] = m_new;
            }
        }
        __syncthreads();

        // ---- PV: wave (hm,cq) -> 16 heads x 128 c-channels, K=32, all-LDS ----
        {
            half8 pf = *(const half8*)(p_lds + (hm * 16 + lr) * PPL + kg * 8);
            float av0 = a_s[hm * 16 + kg * 4 + 0];
            float av1 = a_s[hm * 16 + kg * 4 + 1];
            float av2 = a_s[hm * 16 + kg * 4 + 2];
            float av3 = a_s[hm * 16 + kg * 4 + 3];
            #pragma unroll
            for (int n = 0; n < 8; ++n) {
                oacc[n][0] *= av0; oacc[n][1] *= av1;
                oacc[n][2] *= av2; oacc[n][3] *= av3;
            }
            const int cb = cq * 128 + lr;
            const int sx = (kg ^ (lr & 3)) << 3;
            __builtin_amdgcn_s_setprio(1);
            #pragma unroll
            for (int n = 0; n < 8; ++n) {
                const int c = cb + n * 16;
                half8 vf = *(const half8*)(v_lds + c * KB + sx);
                oacc[n] = __builtin_amdgcn_mfma_f32_16x16x32_f16(pf, vf, oacc[n], 0, 0, 0);
            }
            __builtin_amdgcn_s_setprio(0);
        }
    }

    // ---- epilogue: o = acc/l, lse = m + log(l) ----
    {
        float inv0 = 1.0f / l_s[hm * 16 + kg * 4 + 0];
        float inv1 = 1.0f / l_s[hm * 16 + kg * 4 + 1];
        float inv2 = 1.0f / l_s[hm * 16 + kg * 4 + 2];
        float inv3 = 1.0f / l_s[hm * 16 + kg * 4 + 3];
        #pragma unroll
        for (int n = 0; n < 8; ++n) {
            const int c = cq * 128 + n * 16 + lr;
            float* op = out + (size_t)((b * H_ + h0 + hm * 16 + kg * 4) * NS_ + sp) * (C_ + 1) + c;
            const size_t hstride = (size_t)NS_ * (C_ + 1);
            op[0 * hstride] = oacc[n][0] * inv0;
            op[1 * hstride] = oacc[n][1] * inv1;
            op[2 * hstride] = oacc[n][2] * inv2;
            op[3 * hstride] = oacc[n][3] * inv3;
        }
        if (t < HT)
            out[(size_t)((b * H_ + h0 + t) * NS_ + sp) * (C_ + 1) + C_]
                = m_s[t] + logf(l_s[t]);
    }
}

// ---------------- launcher --------------------------------------------------

extern "C" void kernel_launch(void* const* d_in, const int* in_sizes, int n_in,
                              void* d_out, int out_size, void* d_ws, size_t ws_size,
                              hipStream_t stream) {
    float*       qp        = (float*)d_in[0];
    float*       kbuf      = (float*)d_in[1];
    const float* vbuf      = (const float*)d_in[2];
    const float* cache     = (const float*)d_in[3];
    const int*   positions = (const int*)d_in[4];
    const int*   indptr    = (const int*)d_in[5];
    const int*   indices   = (const int*)d_in[6];
    float*       out       = (float*)d_out;

    const long long tail = (long long)B_ * H_ * NS_ * (C_ + 1);
    const bool use_rope = ((long long)out_size == tail + (long long)B_ * R_);

    if (use_rope) {
        rope_q_kernel<<<(B_ * H_ * HALF_ + 255) / 256, 256, 0, stream>>>(qp, cache, positions);
        rope_k_kernel<<<(B_ * HALF_ + 255) / 256, 256, 0, stream>>>(
            kbuf, cache, positions, indptr, indices, out + tail);
    } else {
        zero_tail_kernel<<<1, 64, 0, stream>>>(out + tail);
    }

    mla_attn_kernel<<<dim3(1024), dim3(512), 0, stream>>>(qp, kbuf, vbuf, indptr, indices, out);
}